// Round 7
// baseline (245.023 us; speedup 1.0000x reference)
//
#include <hip/hip_runtime.h>
#include <stdint.h>

// LSTMBaseline: 2-layer, 1-step LSTM (zero init state) + decoder on MI355X.
//   h0 = lstm(x; W_ih0, b_ih0+b_hh0)   M=16384, K=512,  H=1024
//   h1 = lstm(h0; W_ih1, b_ih1+b_hh1)  K=1024
//   out = h1 @ W_dec^T + b_dec         N=512 (f32 out)
// f32 inputs -> bf16 prepass (x, gate-packed W_ih{0,1}, W_dec), then MFMA
// GEMMs. Round 7: R6 tile geometry UNCHANGED (gated 128x64-out, B=192 rows,
// acc[4][6]; decoder 128x128) but the K-loop is phase-interleaved with an
// LDS double-buffer (80KB -> still 2 blocks/CU): per K-tile, 4 phases of
// {ds_read subtile -> stage next tile's chunks -> s_barrier -> lgkmcnt(0)
// -> setprio 12-MFMA cluster}, ONE counted vmcnt(3) per K-tile (never 0 in
// steady state). f-gate dead (c0=0), W_hh dead (h0=0).

typedef __attribute__((ext_vector_type(8))) __bf16 bf16x8;
typedef __attribute__((ext_vector_type(4))) float f32x4;

#define BM 128
#define BK 64

__device__ __forceinline__ unsigned short f2b(float f) {
    unsigned int x = __builtin_bit_cast(unsigned int, f);
    x = x + 0x7FFFu + ((x >> 16) & 1u);   // RNE
    return (unsigned short)(x >> 16);
}
__device__ __forceinline__ float sigf(float x) { return 1.0f / (1.0f + __expf(-x)); }
__device__ __forceinline__ float tanh_safe(float x) {
    float a = fabsf(x);
    float e = __expf(-2.0f * a);
    float t = (1.0f - e) / (1.0f + e);
    return x < 0.0f ? -t : t;
}

__device__ __forceinline__ void cvt8(const float* __restrict__ s,
                                     unsigned short* __restrict__ d) {
    f32x4 lo = *reinterpret_cast<const f32x4*>(s);
    f32x4 hi = *reinterpret_cast<const f32x4*>(s + 4);
    __attribute__((ext_vector_type(8))) unsigned short v;
    v[0] = f2b(lo[0]); v[1] = f2b(lo[1]); v[2] = f2b(lo[2]); v[3] = f2b(lo[3]);
    v[4] = f2b(hi[0]); v[5] = f2b(hi[1]); v[6] = f2b(hi[2]); v[7] = f2b(hi[3]);
    *reinterpret_cast<__attribute__((ext_vector_type(8))) unsigned short*>(d) = v;
}

__device__ __forceinline__ void gload16(const unsigned short* g, unsigned short* l) {
    __builtin_amdgcn_global_load_lds(
        (const __attribute__((address_space(1))) void*)g,
        (__attribute__((address_space(3))) void*)l,
        16, 0, 0);
}

#define VMW(n)  asm volatile("s_waitcnt vmcnt(" #n ")" ::: "memory")
#define LGKM0() asm volatile("s_waitcnt lgkmcnt(0)" ::: "memory")
#define SB0()   __builtin_amdgcn_sched_barrier(0)
#define BAR()   __builtin_amdgcn_s_barrier()

// ---- pre-pass: f32 -> bf16 linear convert ---------------------------------
__global__ __launch_bounds__(256) void cvt_lin(const float* __restrict__ s,
                                               unsigned short* __restrict__ d,
                                               int n8) {
    int stride = gridDim.x * blockDim.x;
    for (int c = blockIdx.x * blockDim.x + threadIdx.x; c < n8; c += stride)
        cvt8(s + (size_t)c * 8, d + (size_t)c * 8);
}

// ---- pre-pass: gate-pack W (4H x K f32) -> (H/64 groups x 192 x K) bf16 ----
// Group G covers out-cols [G*64, G*64+64). Packed row r in group:
// r = wc*96 + (hsub*3 + gate)*16 + i; hcol = G*64 + wc*32 + hsub*16 + i;
// src row = {0,2H,3H}[gate] + hcol. Matches the GEMM's bv read order.
__global__ __launch_bounds__(256) void pack_w(const float* __restrict__ W,
                                              unsigned short* __restrict__ d,
                                              int K8, int H, int n8) {
    int stride = gridDim.x * blockDim.x;
    for (int c = blockIdx.x * blockDim.x + threadIdx.x; c < n8; c += stride) {
        int dstRow = c / K8, kc = c - dstRow * K8;
        int G = dstRow / 192, r = dstRow - G * 192;
        int wc = r / 96, rr = r - wc * 96;
        int n = rr >> 4, i = rr & 15;
        int hsub = n / 3, gate = n - hsub * 3;
        int goff = (gate == 0) ? 0 : (gate + 1);   // {i,g,o} -> {0,2H,3H}
        int hcol = G * 64 + wc * 32 + hsub * 16 + i;
        cvt8(W + ((size_t)(goff * H + hcol) * K8 + kc) * 8, d + (size_t)c * 8);
    }
}

// ---- fused GEMM: 128-row tile, 4 waves (2Mx2N), phase-interleaved dbuf ----
// GATED=1: B 192 rows (gate-major packed per 64 out-cols); acc[4][6]
//   (n = hsub*3+gate); activation epilogue -> bf16 h. GATED=0: 128x128,
//   B rows = out cols linear; f32 out + bias. K, N compile-time.
template <int GATED, int K, int N>
__global__ __launch_bounds__(256, 2) void gemm_fused(
    const unsigned short* __restrict__ A,   // M x K bf16
    const unsigned short* __restrict__ Wp,  // packed/linear bf16, rows x K
    const float* __restrict__ b0,
    const float* __restrict__ b1,
    void* __restrict__ Ov,
    int M)
{
    constexpr int NFR   = GATED ? 6 : 4;     // col fragments per wave
    constexpr int BROWS = GATED ? 192 : 128; // B tile rows
    constexpr int WCS   = GATED ? 96 : 64;   // B rows per wave-col group
    constexpr int ONB   = GATED ? 64 : 128;  // out cols per block
    constexpr int NBX   = N / ONB;
    constexpr int ACH   = 4;                 // A gloads per thread per tile
    constexpr int BCH   = BROWS / 32;        // B gloads per thread (6 / 4)
    constexpr int AE    = BM * BK;           // A buf elems (8192)
    constexpr int BE    = BROWS * BK;        // B buf elems
    constexpr int NT    = K / BK;

    __shared__ __align__(16) unsigned short sA[2 * AE];
    __shared__ __align__(16) unsigned short sB[2 * BE];

    const int tid  = threadIdx.x;
    const int lane = tid & 63;
    const int w    = tid >> 6;
    const int wr   = w >> 1, wc = w & 1;
    const int l16  = lane & 15, hi8 = lane >> 4;

    // Bijective XCD swizzle (grids are multiples of 8).
    const int cpx  = gridDim.x >> 3;
    const int orig = blockIdx.x;
    const int rid  = (orig & 7) * cpx + (orig >> 3);
    const int bx   = rid % NBX;
    const int by   = rid / NBX;
    const int row0 = by * BM;
    const int n0   = bx * ONB;

    // Staging: chunk u covers row (tid>>3)+u*32 (mod its matrix), k-slot
    // sl=tid&7; global source pre-swizzled (ls = sl^(row&7), row&7==r0&7
    // since stride 32); LDS dest linear per global_load_lds rules.
    const int r0 = tid >> 3, sl = tid & 7;
    const int ls = sl ^ (r0 & 7);
    const unsigned int offA = (unsigned)(row0 + r0) * K + ls * 8;
    const unsigned int offB = (unsigned)((GATED ? bx * BROWS : n0) + r0) * K + ls * 8;

    // STG(u, nbuf, koff): issue chunk u of the K-tile at element offset koff.
#define STG(u, nbuf, koff)                                                     \
    do {                                                                       \
        if ((u) < ACH)                                                         \
            gload16(A + offA + (u) * (32 * K) + (koff),                        \
                    sA + (nbuf) * AE + tid * 8 + (u) * 2048);                  \
        else                                                                   \
            gload16(Wp + offB + ((u) - ACH) * (32 * K) + (koff),               \
                    sB + (nbuf) * BE + tid * 8 + ((u) - ACH) * 2048);          \
    } while (0)

    bf16x8 av[4];
#define LDAV(ks, b_)                                                           \
    do {                                                                       \
        _Pragma("unroll")                                                      \
        for (int m = 0; m < 4; ++m) {                                          \
            int row = wr * 64 + m * 16 + l16;                                  \
            int ps = ((ks) * 4 + hi8) ^ (row & 7);                             \
            av[m] = *reinterpret_cast<const bf16x8*>(                          \
                sA + (b_) * AE + row * BK + ps * 8);                           \
        }                                                                      \
    } while (0)

    f32x4 acc[4][NFR];
#pragma unroll
    for (int m = 0; m < 4; ++m)
#pragma unroll
        for (int n = 0; n < NFR; ++n)
            acc[m][n] = (f32x4){0.f, 0.f, 0.f, 0.f};

    // Prologue: stage tile 0 into buf 0.
#pragma unroll
    for (int u = 0; u < ACH + BCH; ++u) STG(u, 0, 0);

    if constexpr (GATED) {
        bf16x8 bv[3];
#define LDBV3(ks, nh, b_)                                                      \
    do {                                                                       \
        _Pragma("unroll")                                                      \
        for (int j = 0; j < 3; ++j) {                                          \
            int row = wc * WCS + ((nh) * 3 + j) * 16 + l16;                    \
            int ps = ((ks) * 4 + hi8) ^ (row & 7);                             \
            bv[j] = *reinterpret_cast<const bf16x8*>(                          \
                sB + (b_) * BE + row * BK + ps * 8);                           \
        }                                                                      \
    } while (0)
#define MMG(nh)                                                                \
    do {                                                                       \
        __builtin_amdgcn_s_setprio(1);                                         \
        _Pragma("unroll")                                                      \
        for (int m = 0; m < 4; ++m) {                                          \
            _Pragma("unroll")                                                  \
            for (int j = 0; j < 3; ++j)                                        \
                acc[m][(nh) * 3 + j] = __builtin_amdgcn_mfma_f32_16x16x32_bf16(\
                    av[m], bv[j], acc[m][(nh) * 3 + j], 0, 0, 0);              \
        }                                                                      \
        __builtin_amdgcn_s_setprio(0);                                         \
    } while (0)

        for (int t = 0; t < NT; ++t) {
            const int b = t & 1, nb = b ^ 1;
            const int ko = (t + 1) * BK;
            const bool st = (t + 1 < NT);
            // P0: stage 3 -> counted wait for tile t -> reads -> 12 MFMA
            if (st) { STG(0, nb, ko); STG(1, nb, ko); STG(2, nb, ko); VMW(3); }
            else    { VMW(0); }
            BAR(); SB0();
            LDAV(0, b); LDBV3(0, 0, b);
            LGKM0(); SB0();
            MMG(0);
            BAR();
            // P1
            LDBV3(0, 1, b);
            if (st) { STG(3, nb, ko); STG(4, nb, ko); STG(5, nb, ko); }
            BAR(); LGKM0(); SB0();
            MMG(1);
            BAR();
            // P2
            LDAV(1, b); LDBV3(1, 0, b);
            if (st) { STG(6, nb, ko); STG(7, nb, ko); }
            BAR(); LGKM0(); SB0();
            MMG(0);
            BAR();
            // P3
            LDBV3(1, 1, b);
            if (st) { STG(8, nb, ko); STG(9, nb, ko); }
            BAR(); LGKM0(); SB0();
            MMG(1);
            BAR();
        }

        // ---- gated epilogue ----
        unsigned short* O = (unsigned short*)Ov;
#pragma unroll
        for (int hsub = 0; hsub < 2; ++hsub) {
            const int hcol = n0 + wc * 32 + hsub * 16 + l16;
            const float bi = b0[hcol]         + b1[hcol];
            const float bg = b0[2 * N + hcol] + b1[2 * N + hcol];
            const float bo = b0[3 * N + hcol] + b1[3 * N + hcol];
#pragma unroll
            for (int m = 0; m < 4; ++m) {
                int rbase = row0 + wr * 64 + m * 16 + hi8 * 4;
#pragma unroll
                for (int q = 0; q < 4; ++q) {
                    float iv = sigf(acc[m][hsub * 3 + 0][q] + bi);
                    float gv = tanh_safe(acc[m][hsub * 3 + 1][q] + bg);
                    float ov = sigf(acc[m][hsub * 3 + 2][q] + bo);
                    float h  = ov * tanh_safe(iv * gv);
                    O[(size_t)(rbase + q) * N + hcol] = f2b(h);
                }
            }
        }
    } else {
        bf16x8 bv[4];
#define LDBV4(ks, b_)                                                          \
    do {                                                                       \
        _Pragma("unroll")                                                      \
        for (int j = 0; j < 4; ++j) {                                          \
            int row = wc * WCS + j * 16 + l16;                                 \
            int ps = ((ks) * 4 + hi8) ^ (row & 7);                             \
            bv[j] = *reinterpret_cast<const bf16x8*>(                          \
                sB + (b_) * BE + row * BK + ps * 8);                           \
        }                                                                      \
    } while (0)
#define MMD()                                                                  \
    do {                                                                       \
        __builtin_amdgcn_s_setprio(1);                                         \
        _Pragma("unroll")                                                      \
        for (int m = 0; m < 4; ++m) {                                          \
            _Pragma("unroll")                                                  \
            for (int j = 0; j < 4; ++j)                                        \
                acc[m][j] = __builtin_amdgcn_mfma_f32_16x16x32_bf16(           \
                    av[m], bv[j], acc[m][j], 0, 0, 0);                         \
        }                                                                      \
        __builtin_amdgcn_s_setprio(0);                                         \
    } while (0)

        for (int t = 0; t < NT; ++t) {
            const int b = t & 1, nb = b ^ 1;
            const int ko = (t + 1) * BK;
            const bool st = (t + 1 < NT);
            // P0 (ks=0): 16 MFMA
            if (st) { STG(0, nb, ko); STG(1, nb, ko); STG(2, nb, ko); STG(3, nb, ko); VMW(4); }
            else    { VMW(0); }
            BAR(); SB0();
            LDAV(0, b); LDBV4(0, b);
            LGKM0(); SB0();
            MMD();
            BAR();
            // P1 (ks=1)
            LDAV(1, b); LDBV4(1, b);
            if (st) { STG(4, nb, ko); STG(5, nb, ko); STG(6, nb, ko); STG(7, nb, ko); }
            BAR(); LGKM0(); SB0();
            MMD();
            BAR();
        }

        // ---- decoder epilogue ----
        float* O = (float*)Ov;
#pragma unroll
        for (int n = 0; n < 4; ++n) {
            int col = n0 + wc * WCS + n * 16 + l16;
            float bias = b0[col];
#pragma unroll
            for (int m = 0; m < 4; ++m) {
                int rbase = row0 + wr * 64 + m * 16 + hi8 * 4;
#pragma unroll
                for (int q = 0; q < 4; ++q)
                    O[(size_t)(rbase + q) * N + col] = acc[m][n][q] + bias;
            }
        }
    }
#undef STG
#undef LDAV
#undef LDBV3
#undef MMG
#undef LDBV4
#undef MMD
}

extern "C" void kernel_launch(void* const* d_in, const int* in_sizes, int n_in,
                              void* d_out, int out_size, void* d_ws, size_t ws_size,
                              hipStream_t stream) {
    constexpr int M = 16384, D = 512, H = 1024;

    const float* x    = (const float*)d_in[0];
    const float* Wih0 = (const float*)d_in[1];
    // d_in[2] = W_hh0: unused (h0 = 0)
    const float* bih0 = (const float*)d_in[3];
    const float* bhh0 = (const float*)d_in[4];
    const float* Wih1 = (const float*)d_in[5];
    // d_in[6] = W_hh1: unused
    const float* bih1 = (const float*)d_in[7];
    const float* bhh1 = (const float*)d_in[8];
    const float* Wdec = (const float*)d_in[9];
    const float* bdec = (const float*)d_in[10];

    const size_t szH = (size_t)M * H * 2;          // 33.5 MB
    const size_t sw0 = (size_t)3 * H * D * 2;      // 3.1 MB
    const size_t sw1 = (size_t)3 * H * H * 2;      // 6.3 MB

    unsigned short* h0 = (unsigned short*)d_ws;
    unsigned short* h1 = (unsigned short*)((char*)d_ws + szH);
    unsigned short* xb = h1;                       // alias: dead before L1 writes h1
    unsigned short* wp0   = (unsigned short*)((char*)d_ws + 2 * szH);
    unsigned short* wp1   = (unsigned short*)((char*)wp0 + sw0);
    unsigned short* wdecb = (unsigned short*)((char*)wp1 + sw1);

    cvt_lin<<<2048, 256, 0, stream>>>(x, xb, M * D / 8);
    pack_w <<<768,  256, 0, stream>>>(Wih0, wp0, D / 8, H, 3 * H * D / 8);
    pack_w <<<1536, 256, 0, stream>>>(Wih1, wp1, H / 8, H, 3 * H * H / 8);
    cvt_lin<<<256,  256, 0, stream>>>(Wdec, wdecb, D * H / 8);

    // layer 0: K=512; grid = (H/64) x (M/128) = 2048 blocks
    gemm_fused<1, 512, 1024><<<dim3((1024 / 64) * (M / BM)), 256, 0, stream>>>(
        xb, wp0, bih0, bhh0, h0, M);
    // layer 1: K=1024
    gemm_fused<1, 1024, 1024><<<dim3((1024 / 64) * (M / BM)), 256, 0, stream>>>(
        h0, wp1, bih1, bhh1, h1, M);
    // decoder: N=512; grid = (D/128) x (M/128) = 512 blocks
    gemm_fused<0, 1024, 512><<<dim3((512 / 128) * (M / BM)), 256, 0, stream>>>(
        h1, wdecb, bdec, nullptr, (float*)d_out, M);
}

// Round 8
// 234.669 us; speedup vs baseline: 1.0441x; 1.0441x over previous
//
#include <hip/hip_runtime.h>
#include <stdint.h>

// LSTMBaseline: 2-layer, 1-step LSTM (zero init state) + decoder on MI355X.
//   h0 = lstm(x; W_ih0, b_ih0+b_hh0)   M=16384, K=512,  H=1024
//   h1 = lstm(h0; W_ih1, b_ih1+b_hh1)  K=1024
//   out = h1 @ W_dec^T + b_dec         N=512 (f32 out)
// f32 inputs -> bf16 prepass (x, gate-packed W_ih{0,1}, W_dec), then MFMA
// GEMMs. Round 8 = R6 (the best structure so far) + minimum-T3 prefetch:
// LDS double-buffer; tile t+1's global_load_lds issued BEFORE tile t's
// compute; ONE __syncthreads() per K-tile (its built-in vmcnt(0) drain now
// happens a full compute-phase after the loads were issued). No inline-asm
// scheduling -- the three hand-scheduled variants (R4/R5/R7) all regressed.
// f-gate dead (c0=0), W_hh dead (h0=0).

typedef __attribute__((ext_vector_type(8))) __bf16 bf16x8;
typedef __attribute__((ext_vector_type(4))) float f32x4;

#define BM 128
#define BK 64

__device__ __forceinline__ unsigned short f2b(float f) {
    unsigned int x = __builtin_bit_cast(unsigned int, f);
    x = x + 0x7FFFu + ((x >> 16) & 1u);   // RNE
    return (unsigned short)(x >> 16);
}
__device__ __forceinline__ float sigf(float x) { return 1.0f / (1.0f + __expf(-x)); }
__device__ __forceinline__ float tanh_safe(float x) {
    float a = fabsf(x);
    float e = __expf(-2.0f * a);
    float t = (1.0f - e) / (1.0f + e);
    return x < 0.0f ? -t : t;
}

__device__ __forceinline__ void cvt8(const float* __restrict__ s,
                                     unsigned short* __restrict__ d) {
    f32x4 lo = *reinterpret_cast<const f32x4*>(s);
    f32x4 hi = *reinterpret_cast<const f32x4*>(s + 4);
    __attribute__((ext_vector_type(8))) unsigned short v;
    v[0] = f2b(lo[0]); v[1] = f2b(lo[1]); v[2] = f2b(lo[2]); v[3] = f2b(lo[3]);
    v[4] = f2b(hi[0]); v[5] = f2b(hi[1]); v[6] = f2b(hi[2]); v[7] = f2b(hi[3]);
    *reinterpret_cast<__attribute__((ext_vector_type(8))) unsigned short*>(d) = v;
}

__device__ __forceinline__ void gload16(const unsigned short* g, unsigned short* l) {
    __builtin_amdgcn_global_load_lds(
        (const __attribute__((address_space(1))) void*)g,
        (__attribute__((address_space(3))) void*)l,
        16, 0, 0);
}

// ---- pre-pass: f32 -> bf16 linear convert ---------------------------------
__global__ __launch_bounds__(256) void cvt_lin(const float* __restrict__ s,
                                               unsigned short* __restrict__ d,
                                               int n8) {
    int stride = gridDim.x * blockDim.x;
    for (int c = blockIdx.x * blockDim.x + threadIdx.x; c < n8; c += stride)
        cvt8(s + (size_t)c * 8, d + (size_t)c * 8);
}

// ---- pre-pass: gate-pack W (4H x K f32) -> (H/64 groups x 192 x K) bf16 ----
// Group G covers out-cols [G*64, G*64+64). Packed row r in group:
// r = wc*96 + (hsub*3 + gate)*16 + i; hcol = G*64 + wc*32 + hsub*16 + i;
// src row = {0,2H,3H}[gate] + hcol. Matches the GEMM's bv read order.
__global__ __launch_bounds__(256) void pack_w(const float* __restrict__ W,
                                              unsigned short* __restrict__ d,
                                              int K8, int H, int n8) {
    int stride = gridDim.x * blockDim.x;
    for (int c = blockIdx.x * blockDim.x + threadIdx.x; c < n8; c += stride) {
        int dstRow = c / K8, kc = c - dstRow * K8;
        int G = dstRow / 192, r = dstRow - G * 192;
        int wc = r / 96, rr = r - wc * 96;
        int n = rr >> 4, i = rr & 15;
        int hsub = n / 3, gate = n - hsub * 3;
        int goff = (gate == 0) ? 0 : (gate + 1);   // {i,g,o} -> {0,2H,3H}
        int hcol = G * 64 + wc * 32 + hsub * 16 + i;
        cvt8(W + ((size_t)(goff * H + hcol) * K8 + kc) * 8, d + (size_t)c * 8);
    }
}

// ---- fused GEMM: 128-row tile, 4 waves (2Mx2N), prefetch-1 dbuf loop ------
// GATED=1: B 192 rows (gate-major packed per 64 out-cols); acc[4][6]
//   (n = hsub*3+gate); activation epilogue -> bf16 h. GATED=0: 128x128,
//   B rows = out cols linear; f32 out + bias.
template <int GATED>
__global__ __launch_bounds__(256, 2) void gemm_fused(
    const unsigned short* __restrict__ A,   // M x K bf16
    const unsigned short* __restrict__ Wp,  // packed/linear bf16, rows x K
    const float* __restrict__ b0,
    const float* __restrict__ b1,
    void* __restrict__ Ov,
    int M, int K, int N, int NBX)
{
    constexpr int NFR   = GATED ? 6 : 4;     // col fragments per wave
    constexpr int BROWS = GATED ? 192 : 128; // B tile rows
    constexpr int WCS   = GATED ? 96 : 64;   // B rows per wave-col group
    constexpr int ONB   = GATED ? 64 : 128;  // out cols per block
    constexpr int NBCH  = BROWS / 32;        // B gloads per thread (6 / 4)
    constexpr int AE    = BM * BK;           // A buf elems (8192)
    constexpr int BE    = BROWS * BK;        // B buf elems

    __shared__ __align__(16) unsigned short sA[2 * AE];
    __shared__ __align__(16) unsigned short sB[2 * BE];

    const int tid  = threadIdx.x;
    const int lane = tid & 63;
    const int w    = tid >> 6;
    const int wr   = w >> 1, wc = w & 1;
    const int l16  = lane & 15, hi8 = lane >> 4;

    // Bijective XCD swizzle (grids are multiples of 8).
    const int cpx  = gridDim.x >> 3;
    const int orig = blockIdx.x;
    const int rid  = (orig & 7) * cpx + (orig >> 3);
    const int bx   = rid % NBX;
    const int by   = rid / NBX;
    const int row0 = by * BM;
    const int n0   = bx * ONB;

    // Staging: chunk i covers row (tid>>3)+i*32, k-slot sl=tid&7. Global
    // source pre-swizzled (ls = sl^(row&7), row&7==r0&7 since stride 32);
    // LDS dest linear per global_load_lds rules.
    const int r0 = tid >> 3, sl = tid & 7;
    const int ls = sl ^ (r0 & 7);
    const unsigned int strd = 32u * (unsigned)K;
    const unsigned int offA = (unsigned)(row0 + r0) * (unsigned)K + ls * 8;
    const unsigned int offB = (unsigned)((GATED ? bx * BROWS : n0) + r0)
                              * (unsigned)K + ls * 8;

    f32x4 acc[4][NFR];
#pragma unroll
    for (int m = 0; m < 4; ++m)
#pragma unroll
        for (int n = 0; n < NFR; ++n)
            acc[m][n] = (f32x4){0.f, 0.f, 0.f, 0.f};

    // Prologue: stage tile 0 into buf 0; __syncthreads drains vmcnt.
#pragma unroll
    for (int i = 0; i < 4; ++i)
        gload16(A + offA + i * strd, sA + tid * 8 + i * 2048);
#pragma unroll
    for (int i = 0; i < NBCH; ++i)
        gload16(Wp + offB + i * strd, sB + tid * 8 + i * 2048);
    __syncthreads();

    const int NT = K >> 6;
    for (int t = 0; t < NT; ++t) {
        const int b = t & 1, nb = b ^ 1;

        // Prefetch tile t+1 into the other buffer. Safe: buf nb's last
        // readers finished before the barrier that ended iteration t-1.
        if (t + 1 < NT) {
            const unsigned int kn = (unsigned)(t + 1) * BK;
#pragma unroll
            for (int i = 0; i < 4; ++i)
                gload16(A + offA + i * strd + kn,
                        sA + nb * AE + tid * 8 + i * 2048);
#pragma unroll
            for (int i = 0; i < NBCH; ++i)
                gload16(Wp + offB + i * strd + kn,
                        sB + nb * BE + tid * 8 + i * 2048);
        }

        const unsigned short* sAb = sA + b * AE;
        const unsigned short* sBb = sB + b * BE;
#pragma unroll
        for (int ks = 0; ks < 2; ++ks) {
            bf16x8 av[4], bv[NFR];
#pragma unroll
            for (int m = 0; m < 4; ++m) {
                int row = wr * 64 + m * 16 + l16;
                int ps = (ks * 4 + hi8) ^ (row & 7);
                av[m] = *reinterpret_cast<const bf16x8*>(sAb + row * BK + ps * 8);
            }
#pragma unroll
            for (int n = 0; n < NFR; ++n) {
                int row = wc * WCS + n * 16 + l16;
                int ps = (ks * 4 + hi8) ^ (row & 7);
                bv[n] = *reinterpret_cast<const bf16x8*>(sBb + row * BK + ps * 8);
            }
#pragma unroll
            for (int m = 0; m < 4; ++m)
#pragma unroll
                for (int n = 0; n < NFR; ++n)
                    acc[m][n] = __builtin_amdgcn_mfma_f32_16x16x32_bf16(
                        av[m], bv[n], acc[m][n], 0, 0, 0);
        }
        // Single barrier per K-tile: built-in vmcnt(0)+lgkmcnt(0) drain now
        // waits on loads issued a full compute-phase ago (latency hidden),
        // and releases buf b for the next iteration's prefetch.
        __syncthreads();
    }

    // ---- epilogue ----
    if constexpr (GATED) {
        unsigned short* O = (unsigned short*)Ov;
#pragma unroll
        for (int hsub = 0; hsub < 2; ++hsub) {
            const int hcol = n0 + wc * 32 + hsub * 16 + l16;
            const float bi = b0[hcol]         + b1[hcol];
            const float bg = b0[2 * N + hcol] + b1[2 * N + hcol];
            const float bo = b0[3 * N + hcol] + b1[3 * N + hcol];
#pragma unroll
            for (int m = 0; m < 4; ++m) {
                int rbase = row0 + wr * 64 + m * 16 + hi8 * 4;
#pragma unroll
                for (int q = 0; q < 4; ++q) {
                    float iv = sigf(acc[m][hsub * 3 + 0][q] + bi);
                    float gv = tanh_safe(acc[m][hsub * 3 + 1][q] + bg);
                    float ov = sigf(acc[m][hsub * 3 + 2][q] + bo);
                    float h  = ov * tanh_safe(iv * gv);
                    O[(size_t)(rbase + q) * N + hcol] = f2b(h);
                }
            }
        }
    } else {
        float* O = (float*)Ov;
#pragma unroll
        for (int n = 0; n < NFR; ++n) {
            int col = n0 + wc * WCS + n * 16 + l16;
            float bias = b0[col];
#pragma unroll
            for (int m = 0; m < 4; ++m) {
                int rbase = row0 + wr * 64 + m * 16 + hi8 * 4;
#pragma unroll
                for (int q = 0; q < 4; ++q)
                    O[(size_t)(rbase + q) * N + col] = acc[m][n][q] + bias;
            }
        }
    }
}

extern "C" void kernel_launch(void* const* d_in, const int* in_sizes, int n_in,
                              void* d_out, int out_size, void* d_ws, size_t ws_size,
                              hipStream_t stream) {
    constexpr int M = 16384, D = 512, H = 1024;

    const float* x    = (const float*)d_in[0];
    const float* Wih0 = (const float*)d_in[1];
    // d_in[2] = W_hh0: unused (h0 = 0)
    const float* bih0 = (const float*)d_in[3];
    const float* bhh0 = (const float*)d_in[4];
    const float* Wih1 = (const float*)d_in[5];
    // d_in[6] = W_hh1: unused
    const float* bih1 = (const float*)d_in[7];
    const float* bhh1 = (const float*)d_in[8];
    const float* Wdec = (const float*)d_in[9];
    const float* bdec = (const float*)d_in[10];

    const size_t szH = (size_t)M * H * 2;          // 33.5 MB
    const size_t sw0 = (size_t)3 * H * D * 2;      // 3.1 MB
    const size_t sw1 = (size_t)3 * H * H * 2;      // 6.3 MB

    unsigned short* h0 = (unsigned short*)d_ws;
    unsigned short* h1 = (unsigned short*)((char*)d_ws + szH);
    unsigned short* xb = h1;                       // alias: dead before L1 writes h1
    unsigned short* wp0   = (unsigned short*)((char*)d_ws + 2 * szH);
    unsigned short* wp1   = (unsigned short*)((char*)wp0 + sw0);
    unsigned short* wdecb = (unsigned short*)((char*)wp1 + sw1);

    cvt_lin<<<2048, 256, 0, stream>>>(x, xb, M * D / 8);
    pack_w <<<768,  256, 0, stream>>>(Wih0, wp0, D / 8, H, 3 * H * D / 8);
    pack_w <<<1536, 256, 0, stream>>>(Wih1, wp1, H / 8, H, 3 * H * H / 8);
    cvt_lin<<<256,  256, 0, stream>>>(Wdec, wdecb, D * H / 8);

    // layer 0: K=512; grid = (H/64) x (M/128) = 2048 blocks
    gemm_fused<1><<<dim3((H / 64) * (M / BM)), 256, 0, stream>>>(
        xb, wp0, bih0, bhh0, h0, M, D, H, H / 64);
    // layer 1: K=1024
    gemm_fused<1><<<dim3((H / 64) * (M / BM)), 256, 0, stream>>>(
        h0, wp1, bih1, bhh1, h1, M, H, H, H / 64);
    // decoder: N=512; grid = (D/128) x (M/128) = 512 blocks
    gemm_fused<0><<<dim3((D / 128) * (M / BM)), 256, 0, stream>>>(
        h1, wdecb, bdec, nullptr, (float*)d_out, M, H, D, D / 128);
}